// Round 4
// baseline (201.440 us; speedup 1.0000x reference)
//
#include <hip/hip_runtime.h>

// out[p*128 + c] = in[p*128 + max(c - mag, 0)], mag = (int)(15.f * frame_value), mag in [0,14].
// Barrier-free: aligned float4 load per lane; shifted assembly via in-wave
// shuffles (lanes 0-31 = row p, lanes 32-63 = row p+1); wave-uniform
// select on mag&3; edge clamp via vh.x (word-0 lanes already hold channel 0).

#define BLOCK 256
#define GRID  2048

typedef float f32x4 __attribute__((ext_vector_type(4)));

template <int R>
__device__ __forceinline__ void shift_loop(
    const f32x4* __restrict__ in4, f32x4* __restrict__ out4,
    long long tid, long long stride, int iters,
    int hi_l, int lo_l, int s0)
{
    long long i = tid;
    #pragma unroll 4
    for (int it = 0; it < iters; ++it, i += stride) {
        f32x4 v = __builtin_nontemporal_load(&in4[i]);

        f32x4 vh, vl;
        vh.x = __shfl(v.x, hi_l, 64);
        vh.y = __shfl(v.y, hi_l, 64);
        vh.z = __shfl(v.z, hi_l, 64);
        vh.w = __shfl(v.w, hi_l, 64);
        if (R != 0) {
            vl.x = __shfl(v.x, lo_l, 64);
            vl.y = __shfl(v.y, lo_l, 64);
            vl.z = __shfl(v.z, lo_l, 64);
            vl.w = __shfl(v.w, lo_l, 64);
        }

        f32x4 o;
        if (R == 0)      { o.x = vh.x; o.y = vh.y; o.z = vh.z; o.w = vh.w; }
        else if (R == 1) { o.x = vl.w; o.y = vh.x; o.z = vh.y; o.w = vh.z; }
        else if (R == 2) { o.x = vl.z; o.y = vl.w; o.z = vh.x; o.w = vh.y; }
        else             { o.x = vl.y; o.y = vl.z; o.z = vl.w; o.w = vh.x; }

        // Edge clamp: channel (s0+j) <= 0 -> channel 0. Only lanes with
        // lin <= k can trigger; for those vh is word 0, so vh.x == channel 0.
        if (s0 + 0 <= 0) o.x = vh.x;
        if (s0 + 1 <= 0) o.y = vh.x;
        if (s0 + 2 <= 0) o.z = vh.x;
        if (s0 + 3 <= 0) o.w = vh.x;

        __builtin_nontemporal_store(o, &out4[i]);
    }
}

__global__ __launch_bounds__(BLOCK) void translation_shift_shfl(
    const f32x4* __restrict__ in4,
    const float* __restrict__ fv,
    f32x4* __restrict__ out4,
    int iters)
{
    // mag exactly as reference: f32 multiply, truncate toward zero. Wave-uniform.
    const int mag = __builtin_amdgcn_readfirstlane((int)(15.0f * fv[0]));
    const int k = mag >> 2;
    const int r = mag & 3;

    const int lane = (int)(threadIdx.x & 63);
    const int lin  = lane & 31;   // word index within the row this lane owns
    const int rb   = lane & 32;   // row-base lane of this half-wave

    const int h = lin - k;
    const int hi_l = rb + (h > 0 ? h : 0);
    const int lo_l = rb + (h - 1 > 0 ? h - 1 : 0);
    const int s0 = (lin << 2) - mag;   // source channel of element 0

    const long long tid    = (long long)blockIdx.x * BLOCK + threadIdx.x;
    const long long stride = (long long)GRID * BLOCK;

    if (r == 0)      shift_loop<0>(in4, out4, tid, stride, iters, hi_l, lo_l, s0);
    else if (r == 1) shift_loop<1>(in4, out4, tid, stride, iters, hi_l, lo_l, s0);
    else if (r == 2) shift_loop<2>(in4, out4, tid, stride, iters, hi_l, lo_l, s0);
    else             shift_loop<3>(in4, out4, tid, stride, iters, hi_l, lo_l, s0);
}

extern "C" void kernel_launch(void* const* d_in, const int* in_sizes, int n_in,
                              void* d_out, int out_size, void* d_ws, size_t ws_size,
                              hipStream_t stream) {
    const f32x4* x4 = (const f32x4*)d_in[0];   // [1,1024,1024,128] f32
    const float* fv = (const float*)d_in[1];   // scalar f32
    f32x4* out4 = (f32x4*)d_out;

    const long long n4 = (long long)out_size / 4;        // 33,554,432 float4s
    // n4 = 2048*256*64 exactly; per-thread iteration count:
    const int iters = (int)(n4 / ((long long)GRID * BLOCK));

    translation_shift_shfl<<<GRID, BLOCK, 0, stream>>>(x4, fv, out4, iters);
}

// Round 5
// 185.602 us; speedup vs baseline: 1.0853x; 1.0853x over previous
//
#include <hip/hip_runtime.h>

// out[p*128 + c] = in[p*128 + max(c - mag, 0)], mag = (int)(15.f * frame_value), mag in [0,14].
// Pure-stream structure: block-contiguous 32KiB tiles, 8 NT float4 loads in
// flight per lane, minimal 4-shuffle in-wave assembly (lanes 0-31 = row p,
// lanes 32-63 = row p+1), NT stores. No LDS, no barriers.

#define BLOCK  256
#define GRID   2048
#define UNROLL 8

typedef float f32x4 __attribute__((ext_vector_type(4)));

template <int R>
__device__ __forceinline__ f32x4 assemble(f32x4 v, int hi_l, int lo_l, int s0) {
    f32x4 o;
    const float vhx = __shfl(v.x, hi_l, 64);   // always needed (clamp source)
    if (R == 0) {
        o.x = vhx;
        o.y = __shfl(v.y, hi_l, 64);
        o.z = __shfl(v.z, hi_l, 64);
        o.w = __shfl(v.w, hi_l, 64);
    } else if (R == 1) {
        o.x = __shfl(v.w, lo_l, 64);
        o.y = vhx;
        o.z = __shfl(v.y, hi_l, 64);
        o.w = __shfl(v.z, hi_l, 64);
    } else if (R == 2) {
        o.x = __shfl(v.z, lo_l, 64);
        o.y = __shfl(v.w, lo_l, 64);
        o.z = vhx;
        o.w = __shfl(v.y, hi_l, 64);
    } else {
        o.x = __shfl(v.y, lo_l, 64);
        o.y = __shfl(v.z, lo_l, 64);
        o.z = __shfl(v.w, lo_l, 64);
        o.w = vhx;
    }
    // Edge clamp: source channel (s0+j) <= 0 -> channel 0. Triggering lanes
    // have hi_l at their row base, so vhx == channel 0 there.
    if (s0 + 0 <= 0) o.x = vhx;
    if (s0 + 1 <= 0) o.y = vhx;
    if (s0 + 2 <= 0) o.z = vhx;
    if (s0 + 3 <= 0) o.w = vhx;
    return o;
}

template <int R>
__device__ __forceinline__ void shift_loop(
    const f32x4* __restrict__ in4, f32x4* __restrict__ out4,
    int ntiles, int hi_l, int lo_l, int s0)
{
    const int t = (int)threadIdx.x;
    for (int tile = blockIdx.x; tile < ntiles; tile += GRID) {
        const long long base = (long long)tile * (BLOCK * UNROLL) + t;

        f32x4 v[UNROLL];
        #pragma unroll
        for (int j = 0; j < UNROLL; ++j)
            v[j] = __builtin_nontemporal_load(&in4[base + j * BLOCK]);

        #pragma unroll
        for (int j = 0; j < UNROLL; ++j) {
            f32x4 o = assemble<R>(v[j], hi_l, lo_l, s0);
            __builtin_nontemporal_store(o, &out4[base + j * BLOCK]);
        }
    }
}

__global__ __launch_bounds__(BLOCK) void translation_shift_v5(
    const f32x4* __restrict__ in4,
    const float* __restrict__ fv,
    f32x4* __restrict__ out4,
    int ntiles)
{
    // mag exactly as reference: f32 multiply, truncate toward zero. Wave-uniform.
    const int mag = __builtin_amdgcn_readfirstlane((int)(15.0f * fv[0]));
    const int k = mag >> 2;
    const int r = mag & 3;

    const int lane = (int)(threadIdx.x & 63);
    const int lin  = lane & 31;   // float4 index within this lane's row
    const int rb   = lane & 32;   // row-base lane of this half-wave

    const int h = lin - k;
    const int hi_l = rb + (h > 0 ? h : 0);
    const int lo_l = rb + (h - 1 > 0 ? h - 1 : 0);
    const int s0 = (lin << 2) - mag;   // source channel of element 0

    if (r == 0)      shift_loop<0>(in4, out4, ntiles, hi_l, lo_l, s0);
    else if (r == 1) shift_loop<1>(in4, out4, ntiles, hi_l, lo_l, s0);
    else if (r == 2) shift_loop<2>(in4, out4, ntiles, hi_l, lo_l, s0);
    else             shift_loop<3>(in4, out4, ntiles, hi_l, lo_l, s0);
}

extern "C" void kernel_launch(void* const* d_in, const int* in_sizes, int n_in,
                              void* d_out, int out_size, void* d_ws, size_t ws_size,
                              hipStream_t stream) {
    const f32x4* x4 = (const f32x4*)d_in[0];   // [1,1024,1024,128] f32
    const float* fv = (const float*)d_in[1];   // scalar f32
    f32x4* out4 = (f32x4*)d_out;

    const long long n4 = (long long)out_size / 4;           // 33,554,432 float4s
    const int ntiles = (int)(n4 / (BLOCK * UNROLL));        // 16,384 (exact)

    translation_shift_v5<<<GRID, BLOCK, 0, stream>>>(x4, fv, out4, ntiles);
}

// Round 6
// 184.845 us; speedup vs baseline: 1.0898x; 1.0041x over previous
//
#include <hip/hip_runtime.h>

// out[p*128 + c] = in[p*128 + max(c - mag, 0)], mag = (int)(15.f * frame_value), mag in [0,14].
// Block-contiguous 32KiB tiles, software-pipelined across tiles: next tile's
// 8 NT loads issue before current tile's assemble+store, so VMEM stays busy
// across the phase boundary. 4-shuffle in-wave assembly, NT stores.

#define BLOCK  256
#define GRID   2048
#define UNROLL 8

typedef float f32x4 __attribute__((ext_vector_type(4)));

template <int R>
__device__ __forceinline__ f32x4 assemble(f32x4 v, int hi_l, int lo_l, int s0) {
    f32x4 o;
    const float vhx = __shfl(v.x, hi_l, 64);   // always needed (clamp source)
    if (R == 0) {
        o.x = vhx;
        o.y = __shfl(v.y, hi_l, 64);
        o.z = __shfl(v.z, hi_l, 64);
        o.w = __shfl(v.w, hi_l, 64);
    } else if (R == 1) {
        o.x = __shfl(v.w, lo_l, 64);
        o.y = vhx;
        o.z = __shfl(v.y, hi_l, 64);
        o.w = __shfl(v.z, hi_l, 64);
    } else if (R == 2) {
        o.x = __shfl(v.z, lo_l, 64);
        o.y = __shfl(v.w, lo_l, 64);
        o.z = vhx;
        o.w = __shfl(v.y, hi_l, 64);
    } else {
        o.x = __shfl(v.y, lo_l, 64);
        o.y = __shfl(v.z, lo_l, 64);
        o.z = __shfl(v.w, lo_l, 64);
        o.w = vhx;
    }
    // Edge clamp: source channel (s0+j) <= 0 -> channel 0. Triggering lanes
    // have hi_l at their row base, so vhx == channel 0 there.
    if (s0 + 0 <= 0) o.x = vhx;
    if (s0 + 1 <= 0) o.y = vhx;
    if (s0 + 2 <= 0) o.z = vhx;
    if (s0 + 3 <= 0) o.w = vhx;
    return o;
}

template <int R>
__device__ __forceinline__ void shift_loop(
    const f32x4* __restrict__ in4, f32x4* __restrict__ out4,
    int ntiles, int hi_l, int lo_l, int s0)
{
    const int t = (int)threadIdx.x;

    int tile = blockIdx.x;
    long long base = (long long)tile * (BLOCK * UNROLL) + t;

    f32x4 vA[UNROLL];
    #pragma unroll
    for (int j = 0; j < UNROLL; ++j)
        vA[j] = __builtin_nontemporal_load(&in4[base + j * BLOCK]);

    for (; tile < ntiles; ) {
        const int next = tile + GRID;
        const long long nbase = (long long)next * (BLOCK * UNROLL) + t;

        f32x4 vB[UNROLL];
        if (next < ntiles) {
            #pragma unroll
            for (int j = 0; j < UNROLL; ++j)
                vB[j] = __builtin_nontemporal_load(&in4[nbase + j * BLOCK]);
        }

        #pragma unroll
        for (int j = 0; j < UNROLL; ++j) {
            f32x4 o = assemble<R>(vA[j], hi_l, lo_l, s0);
            __builtin_nontemporal_store(o, &out4[base + j * BLOCK]);
        }

        #pragma unroll
        for (int j = 0; j < UNROLL; ++j) vA[j] = vB[j];

        tile = next;
        base = nbase;
    }
}

__global__ __launch_bounds__(BLOCK) void translation_shift_v6(
    const f32x4* __restrict__ in4,
    const float* __restrict__ fv,
    f32x4* __restrict__ out4,
    int ntiles)
{
    // mag exactly as reference: f32 multiply, truncate toward zero. Wave-uniform.
    const int mag = __builtin_amdgcn_readfirstlane((int)(15.0f * fv[0]));
    const int k = mag >> 2;
    const int r = mag & 3;

    const int lane = (int)(threadIdx.x & 63);
    const int lin  = lane & 31;   // float4 index within this lane's row
    const int rb   = lane & 32;   // row-base lane of this half-wave

    const int h = lin - k;
    const int hi_l = rb + (h > 0 ? h : 0);
    const int lo_l = rb + (h - 1 > 0 ? h - 1 : 0);
    const int s0 = (lin << 2) - mag;   // source channel of element 0

    if (r == 0)      shift_loop<0>(in4, out4, ntiles, hi_l, lo_l, s0);
    else if (r == 1) shift_loop<1>(in4, out4, ntiles, hi_l, lo_l, s0);
    else if (r == 2) shift_loop<2>(in4, out4, ntiles, hi_l, lo_l, s0);
    else             shift_loop<3>(in4, out4, ntiles, hi_l, lo_l, s0);
}

extern "C" void kernel_launch(void* const* d_in, const int* in_sizes, int n_in,
                              void* d_out, int out_size, void* d_ws, size_t ws_size,
                              hipStream_t stream) {
    const f32x4* x4 = (const f32x4*)d_in[0];   // [1,1024,1024,128] f32
    const float* fv = (const float*)d_in[1];   // scalar f32
    f32x4* out4 = (f32x4*)d_out;

    const long long n4 = (long long)out_size / 4;           // 33,554,432 float4s
    const int ntiles = (int)(n4 / (BLOCK * UNROLL));        // 16,384 (exact)

    translation_shift_v6<<<GRID, BLOCK, 0, stream>>>(x4, fv, out4, ntiles);
}